// Round 5
// baseline (4166.693 us; speedup 1.0000x reference)
//
#include <hip/hip_runtime.h>
#include <cstdint>
#include <cstddef>

#define B_   2
#define N_   8192
#define M_   2048
#define K_   32
#define C0_  64
#define C1_  128
#define C2_  256
#define CIN_ 67

// Exact-match distance: reference computes sum((a-b)**2, axis=-1) in f32 as
// ((dx^2 + dy^2) + dz^2) with no FMA contraction. _rn intrinsics forbid
// contract-fast fma fusion (would flip argmax / radius-boundary decisions).
__device__ __forceinline__ float sqdist_rn(float ax, float ay, float az,
                                           float bx, float by, float bz) {
  float dx = __fsub_rn(ax, bx);
  float dy = __fsub_rn(ay, by);
  float dz = __fsub_rn(az, bz);
  return __fadd_rn(__fadd_rn(__fmul_rn(dx, dx), __fmul_rn(dy, dy)),
                   __fmul_rn(dz, dz));
}

__device__ __forceinline__ int morton8(int ix, int iy, int iz) {
  int m = 0;
#pragma unroll
  for (int b = 0; b < 3; ++b) {
    m |= (((ix >> b) & 1) << (3 * b + 2)) | (((iy >> b) & 1) << (3 * b + 1)) |
         (((iz >> b) & 1) << (3 * b + 0));
  }
  return m;
}

// Wave-64 max of a non-negative float via DPP; result valid in lane 63,
// returned broadcast via readlane. bound_ctrl=false + old=self => invalid
// lanes contribute max(v,v)=v.
__device__ __forceinline__ float wave_max_f32_dpp(float v) {
  int x = __float_as_int(v);
#define FPS_STEP(ctrl)                                                      \
  {                                                                         \
    int y = __builtin_amdgcn_update_dpp(x, x, ctrl, 0xf, 0xf, false);       \
    x = __float_as_int(fmaxf(__int_as_float(x), __int_as_float(y)));        \
  }
  FPS_STEP(0x111)  // row_shr:1
  FPS_STEP(0x112)  // row_shr:2
  FPS_STEP(0x114)  // row_shr:4
  FPS_STEP(0x118)  // row_shr:8
  FPS_STEP(0x142)  // row_bcast:15
  FPS_STEP(0x143)  // row_bcast:31
#undef FPS_STEP
  return __int_as_float(__builtin_amdgcn_readlane(x, 63));
}

// ---------------------------------------------------------------------------
// 1) Furthest point sampling: exact spatial pruning + DPP reductions +
//    ONE barrier per iteration, no serialized per-wave stage.
//    One block (1024 thr, 16 waves) per batch.
//    Setup: counting-sort by 8^3 Morton cell into LDS float4{x,y,z,pid};
//    thread t owns sorted points [8t,8t+8) in registers + bounding sphere.
//    Scatter order is atomic-nondeterministic but output-invariant (exact
//    min updates; skips provably no-op; ties break on ORIGINAL index).
//    Per iteration:
//      - all threads: conservative sphere skip test vs last winner; dirty
//        threads redo exact 8-pt update + per-thread candidate.
//      - dirty WAVES re-reduce (DPP f32 max + ballot tie -> min pid) and
//        repack the wave key; clean waves keep cached key (valid: their max
//        is unchanged; the winner's wave is always dirty since its d -> 0).
//      - lane0 writes the u64 key (d_bits<<26 | (8191-pid)<<13 | pos) into
//        parity-double-buffered slot sKey[it&1][w]. (Reads of parity p at
//        iter it are fenced from the next writes to p (it+2) by barrier
//        it+1 -> single barrier suffices.)
//      - ONE __syncthreads(); then ALL 16 waves redundantly reduce the 16
//        slots (4-step row-16 DPP u64 max), readlane the winner pos, and
//        fetch winner coords themselves with one ds_read_b128.
//      - t0 logs coords into write-only snew ring (dumped at the end).
//    Tie-break everywhere == jnp.argmax first-occurrence.
// ---------------------------------------------------------------------------
__global__ __launch_bounds__(1024, 1) void fps_kernel(const float* __restrict__ xyz,
                                                      float* __restrict__ new_xyz) {
  const int b = blockIdx.x;
  const int t = threadIdx.x;
  const int lane = t & 63;
  const int w = t >> 6;
  const float* xb = xyz + (size_t)b * N_ * 3;

  __shared__ float4 spt[N_];                   // 128 KiB sorted {x,y,z,pid}
  __shared__ int hist[512];
  __shared__ int boff[512];
  __shared__ int wsum[8];
  __shared__ unsigned long long sKey[2][16];   // parity-double-buffered slots
  __shared__ float snew[M_ * 3];               // winner ring (write-only in loop)

  // ---- counting sort by morton cell ----
  if (t < 512) hist[t] = 0;
  __syncthreads();
#pragma unroll
  for (int rr = 0; rr < 8; ++rr) {
    int i = rr * 1024 + t;
    float X = xb[i * 3 + 0], Y = xb[i * 3 + 1], Z = xb[i * 3 + 2];
    int ix = min(7, max(0, (int)(X * 8.0f)));
    int iy = min(7, max(0, (int)(Y * 8.0f)));
    int iz = min(7, max(0, (int)(Z * 8.0f)));
    atomicAdd(&hist[morton8(ix, iy, iz)], 1);
  }
  __syncthreads();
  // exclusive scan of 512 bins (8 active waves)
  {
    int ov = (t < 512) ? hist[t] : 0;
    int v = ov;
#pragma unroll
    for (int off = 1; off < 64; off <<= 1) {
      int n = __shfl_up(v, off);
      if (lane >= off) v += n;
    }
    if (t < 512 && lane == 63) wsum[w] = v;
    __syncthreads();
    if (t == 0) {
      int acc = 0;
#pragma unroll
      for (int j = 0; j < 8; ++j) { int x0 = wsum[j]; wsum[j] = acc; acc += x0; }
    }
    __syncthreads();
    if (t < 512) boff[t] = v - ov + wsum[w];
  }
  __syncthreads();
#pragma unroll
  for (int rr = 0; rr < 8; ++rr) {
    int i = rr * 1024 + t;
    float X = xb[i * 3 + 0], Y = xb[i * 3 + 1], Z = xb[i * 3 + 2];
    int ix = min(7, max(0, (int)(X * 8.0f)));
    int iy = min(7, max(0, (int)(Y * 8.0f)));
    int iz = min(7, max(0, (int)(Z * 8.0f)));
    int pos = atomicAdd(&boff[morton8(ix, iy, iz)], 1);
    float4 v4; v4.x = X; v4.y = Y; v4.z = Z; v4.w = __int_as_float(i);
    spt[pos] = v4;
  }
  if (t == 0) {
    snew[0] = xb[0]; snew[1] = xb[1]; snew[2] = xb[2];  // first index = 0
  }
  __syncthreads();

  // ---- per-thread bucket: 8 points into registers + bounding sphere ----
  float px[8], py[8], pz[8], d[8];
  int pid[8];
#pragma unroll
  for (int k = 0; k < 8; ++k) {
    float4 v4 = spt[8 * t + k];
    px[k] = v4.x; py[k] = v4.y; pz[k] = v4.z; pid[k] = __float_as_int(v4.w);
    d[k] = 1e10f;  // == f32(10000000000.0), matches jnp init exactly
  }
  float cx = 0.f, cy = 0.f, cz = 0.f;
#pragma unroll
  for (int k = 0; k < 8; ++k) { cx += px[k]; cy += py[k]; cz += pz[k]; }
  cx *= 0.125f; cy *= 0.125f; cz *= 0.125f;
  float r2m = 0.f;
#pragma unroll
  for (int k = 0; k < 8; ++k) {
    float dx = px[k] - cx, dy = py[k] - cy, dz = pz[k] - cz;
    r2m = fmaxf(r2m, dx * dx + dy * dy + dz * dz);
  }
  const float rad = sqrtf(r2m) * 1.00002f + 1e-12f;

  // cached per-thread candidate max (bd) and cached wave key (wkey).
  // bd=1e10 => iter 1 never skips anywhere, so wkey is set before any
  // clean-wave reuse and every slot is written before first read.
  float bd = 1e10f;
  unsigned long long wkey = 0ull;

  float lx = xb[0], ly = xb[1], lz = xb[2];

  for (int it = 1; it < M_; ++it) {
    const int wp = it & 1;

    // ---- conservative skip test (pruning-quality precision only) ----
    float ex = lx - cx, ey = ly - cy, ez = lz - cz;
    float dc2 = ex * ex + ey * ey + ez * ez;
    float s = sqrtf(dc2) - rad;
    bool skip = (s > 0.f) && (s * s > bd * 1.0001f);
    int bpid = 0, bpos = 0;
    if (!skip) {
      float nbd = -1.f; int nbi = 0x7FFFFFFF, nbp = 0;
#pragma unroll
      for (int k = 0; k < 8; ++k) {
        float dist = sqdist_rn(px[k], py[k], pz[k], lx, ly, lz);
        float dm = fminf(d[k], dist);
        d[k] = dm;
        bool take = (dm > nbd) || (dm == nbd && pid[k] < nbi);
        nbd = take ? dm : nbd;
        nbi = take ? pid[k] : nbi;
        nbp = take ? (8 * t + k) : nbp;
      }
      bd = nbd; bpid = nbi; bpos = nbp;
    }
    unsigned long long dirty = __ballot(!skip);
    if (dirty != 0ull) {  // wave-uniform: refresh the cached wave key
      float wmax = wave_max_f32_dpp(bd);
      unsigned long long tied = __ballot(!skip ? (bd == wmax) : false);
      // note: clean lanes may also hold bd==wmax with a stale bpid; mask to
      // dirty lanes only is WRONG in general -- a clean lane's bd is still
      // the true max of its bucket, and its pid/pos must compete. Recover
      // them: clean lanes recompute candidate lazily if tied.
      unsigned long long tiedAll = __ballot(bd == wmax);
      if (tiedAll != tied) {
        // rare: a clean lane ties the wave max; rebuild its candidate
        if (skip && bd == wmax) {
          float nbd = -1.f; int nbi = 0x7FFFFFFF, nbp = 0;
#pragma unroll
          for (int k = 0; k < 8; ++k) {
            float dm = d[k];
            bool take = (dm > nbd) || (dm == nbd && pid[k] < nbi);
            nbd = take ? dm : nbd;
            nbi = take ? pid[k] : nbi;
            nbp = take ? (8 * t + k) : nbp;
          }
          bpid = nbi; bpos = nbp;
        }
        tied = tiedAll;
      }
      int bestpid = 0x7FFFFFFF, wl = 0;
      while (tied) {
        int l = __ffsll(tied) - 1;
        tied &= tied - 1;
        int p = __builtin_amdgcn_readlane(bpid, l);
        if (p < bestpid) { bestpid = p; wl = l; }
      }
      int wpos = __builtin_amdgcn_readlane(bpos, wl);
      wkey = ((unsigned long long)(unsigned)__float_as_int(wmax) << 26) |
             ((unsigned long long)(unsigned)(8191 - bestpid) << 13) |
             (unsigned long long)(unsigned)wpos;
    }
    if (lane == 0) sKey[wp][w] = wkey;
    __syncthreads();  // the ONLY barrier: slot writes -> slot reads

    // ---- all waves redundantly reduce the 16 slots (row-16 DPP u64) ----
    {
      unsigned long long key = sKey[wp][lane & 15];
#define FPS_STEP2(ctrl)                                                        \
      {                                                                        \
        int klo = (int)(unsigned)key, khi = (int)(unsigned)(key >> 32);        \
        int olo = __builtin_amdgcn_update_dpp(klo, klo, ctrl, 0xf, 0xf, false);\
        int ohi = __builtin_amdgcn_update_dpp(khi, khi, ctrl, 0xf, 0xf, false);\
        unsigned long long okey =                                              \
            ((unsigned long long)(unsigned)ohi << 32) | (unsigned)olo;         \
        if (okey > key) key = okey;                                            \
      }
      FPS_STEP2(0x111)  // row_shr:1
      FPS_STEP2(0x112)  // row_shr:2
      FPS_STEP2(0x114)  // row_shr:4
      FPS_STEP2(0x118)  // row_shr:8
#undef FPS_STEP2
      int winPos = __builtin_amdgcn_readlane((int)(unsigned)key, 15) & 8191;
      float4 c = spt[winPos];  // wave-uniform addr -> broadcast b128
      lx = c.x; ly = c.y; lz = c.z;
    }
    if (t == 0) {
      snew[it * 3 + 0] = lx;
      snew[it * 3 + 1] = ly;
      snew[it * 3 + 2] = lz;
    }
  }
  __syncthreads();

  // ---- coalesced dump of selected coords ----
  for (int i = t; i < M_ * 3; i += 1024) {
    new_xyz[(size_t)b * M_ * 3 + i] = snew[i];
  }
}

// ---------------------------------------------------------------------------
// 2) Fused ball-query + grouping + MLP(67->128 relu ->256) + max over K.
//    One block (256 thr) per centroid. Ball query: wave w scans index chunk
//    [w*2048,(w+1)*2048) in order, ballot-appends first <=32 valid to its own
//    LDS list; lists concat in wave order == global index order (pointnet2
//    first-K semantics). Writes pre-BN pooled features TRANSPOSED into the
//    final (B,C2,M) output region (no scratch needed).
// ---------------------------------------------------------------------------
__global__ __launch_bounds__(256) void mlp_kernel(const float* __restrict__ xyz,
                                                  const float* __restrict__ x,
                                                  const float* __restrict__ W1,
                                                  const float* __restrict__ b1,
                                                  const float* __restrict__ W2,
                                                  const float* __restrict__ b2,
                                                  const float* __restrict__ new_xyz,
                                                  float* __restrict__ outp) {
  __shared__ float sGRed[32 * 69];   // group tile; unioned w/ 8x256 max-red
  __shared__ float sU[128 * 69];     // W1 staged; unioned w/ 32x256 W2 tile
  __shared__ float sH1[32 * 132];
  __shared__ int sWIdx[4][K_];
  __shared__ int sWCnt[4];
  __shared__ int sIdx[K_];
  __shared__ float sQ[3];

  const int gm = blockIdx.x;
  const int b = gm >> 11;    // M_ = 2048
  const int m = gm & 2047;
  const int t = threadIdx.x;
  const int lane = t & 63;
  const int w = t >> 6;
  const float* xb = xyz + (size_t)b * N_ * 3;

  if (t < 3) sQ[t] = new_xyz[(size_t)gm * 3 + t];
  __syncthreads();
  const float qx = sQ[0], qy = sQ[1], qz = sQ[2];
  // (float)(0.1*0.1) = 0x3C23D70A; 0.1f*0.1f rounds differently — wrong.
  const float R2 = (float)(0.1 * 0.1);

  // ---- ball query ----
  {
    int cnt = 0;
    const int cbeg = w * 2048, cend = cbeg + 2048;
    for (int base = cbeg; base < cend; base += 64) {
      int p = base + lane;
      float d2 = sqdist_rn(qx, qy, qz, xb[p * 3 + 0], xb[p * 3 + 1], xb[p * 3 + 2]);
      bool valid = d2 < R2;
      unsigned long long mask = __ballot(valid);
      if (valid) {
        int pos = cnt + __popcll(mask & ((1ull << lane) - 1ull));
        if (pos < K_) sWIdx[w][pos] = p;
      }
      cnt += __popcll(mask);
      if (cnt >= K_) break;  // wave-uniform
    }
    if (lane == 0) sWCnt[w] = (cnt < K_) ? cnt : K_;
  }
  __syncthreads();
  if (t < K_) {
    int c0 = sWCnt[0], c1 = sWCnt[1], c2 = sWCnt[2], c3 = sWCnt[3];
    int s1 = c0 + c1, s2 = s1 + c2, s3 = s2 + c3;
    int j = t, idx;
    if (j < c0) idx = sWIdx[0][j];
    else if (j < s1) idx = sWIdx[1][j - c0];
    else if (j < s2) idx = sWIdx[2][j - s1];
    else if (j < s3) idx = sWIdx[3][j - s2];
    else {
      int fw = c0 ? 0 : (c1 ? 1 : (c2 ? 2 : 3));
      idx = (s3 > 0) ? sWIdx[fw][0] : 0;  // fill with first valid index
    }
    sIdx[j] = idx;
  }
  __syncthreads();

  // ---- grouping: rel coords + features into sGRed (32 x 69 padded) ----
  if (t < K_) {
    int id = sIdx[t];
    sGRed[t * 69 + 0] = xb[id * 3 + 0] - qx;
    sGRed[t * 69 + 1] = xb[id * 3 + 1] - qy;
    sGRed[t * 69 + 2] = xb[id * 3 + 2] - qz;
  }
  {
    int r = t & 31;
    int c0 = (t >> 5) * 8;
    int id = sIdx[r];
    const float* xf = x + ((size_t)b * C0_ + c0) * N_ + id;
#pragma unroll
    for (int j = 0; j < 8; ++j) sGRed[r * 69 + 3 + c0 + j] = xf[(size_t)j * N_];
  }
  for (int i = t; i < C1_ * CIN_; i += 256) {
    sU[(i / CIN_) * 69 + (i % CIN_)] = W1[i];
  }
  __syncthreads();

  const int ol = t & 31;  // output-lane: o = ol + 32*j
  const int rg = t >> 5;  // row group: rows rg*4 .. rg*4+3

  // ---- layer 1: h1 = relu(G @ W1^T + b1), 4 rows x 4 outs per thread ----
  float acc[4][4] = {{0.f}};
  for (int c = 0; c < CIN_; ++c) {
    float g[4], wv[4];
#pragma unroll
    for (int i = 0; i < 4; ++i) g[i] = sGRed[(rg * 4 + i) * 69 + c];
#pragma unroll
    for (int j = 0; j < 4; ++j) wv[j] = sU[(ol + 32 * j) * 69 + c];
#pragma unroll
    for (int i = 0; i < 4; ++i)
#pragma unroll
      for (int j = 0; j < 4; ++j) acc[i][j] += g[i] * wv[j];
  }
#pragma unroll
  for (int j = 0; j < 4; ++j) {
    float bias = b1[ol + 32 * j];
#pragma unroll
    for (int i = 0; i < 4; ++i) {
      float v = acc[i][j] + bias;
      sH1[(rg * 4 + i) * 132 + ol + 32 * j] = fmaxf(v, 0.0f);
    }
  }

  // ---- layer 2: h2 = h1 @ W2^T, 4 rows x 8 outs per thread ----
  float acc2[4][8] = {{0.f}};
  for (int ct = 0; ct < 4; ++ct) {
    __syncthreads();  // sU reuse safe; (ct==0) also covers sH1 writes
    const float4* w4 = (const float4*)(W2 + (size_t)t * C1_ + ct * 32);
#pragma unroll
    for (int jj = 0; jj < 8; ++jj) {
      float4 v = w4[jj];
      sU[(jj * 4 + 0) * 256 + t] = v.x;
      sU[(jj * 4 + 1) * 256 + t] = v.y;
      sU[(jj * 4 + 2) * 256 + t] = v.z;
      sU[(jj * 4 + 3) * 256 + t] = v.w;
    }
    __syncthreads();
    for (int cc = 0; cc < 32; ++cc) {
      float h[4], wv[8];
#pragma unroll
      for (int i = 0; i < 4; ++i) h[i] = sH1[(rg * 4 + i) * 132 + ct * 32 + cc];
#pragma unroll
      for (int j = 0; j < 8; ++j) wv[j] = sU[cc * 256 + ol + 32 * j];
#pragma unroll
      for (int i = 0; i < 4; ++i)
#pragma unroll
        for (int j = 0; j < 8; ++j) acc2[i][j] += h[i] * wv[j];
    }
  }

  // ---- max over K, + b2 (max(x)+c == max(x+c): RN is monotone) ----
  __syncthreads();  // group tile dead; reuse sGRed as reduction buffer
#pragma unroll
  for (int j = 0; j < 8; ++j) {
    float pm = acc2[0][j];
#pragma unroll
    for (int i = 1; i < 4; ++i) pm = fmaxf(pm, acc2[i][j]);
    sGRed[rg * 256 + ol + 32 * j] = pm;
  }
  __syncthreads();
  {
    int o = t;
    float v = sGRed[o];
#pragma unroll
    for (int g = 1; g < 8; ++g) v = fmaxf(v, sGRed[g * 256 + o]);
    v += b2[o];
    // transposed store into final (B, C2, M) layout (pre-BN)
    outp[((size_t)(b * C2_ + o)) * M_ + m] = v;
  }
}

// ---------------------------------------------------------------------------
// 3) BN stats per channel (deterministic, double accum). One block / channel.
// ---------------------------------------------------------------------------
__global__ __launch_bounds__(256) void bn_stats_kernel(const float* __restrict__ outp,
                                                       const float* __restrict__ gamma,
                                                       float* __restrict__ stats) {
  const int o = blockIdx.x;
  const int t = threadIdx.x;
  double s = 0.0, s2 = 0.0;
  for (int b = 0; b < B_; ++b) {
    const float* p = outp + ((size_t)(b * C2_ + o)) * M_;
    for (int i = t; i < M_; i += 256) {
      float v = p[i];
      s += (double)v;
      s2 += (double)v * (double)v;
    }
  }
#pragma unroll
  for (int off = 32; off > 0; off >>= 1) {
    s += __shfl_xor(s, off);
    s2 += __shfl_xor(s2, off);
  }
  __shared__ double aS[4], aS2[4];
  if ((t & 63) == 0) { aS[t >> 6] = s; aS2[t >> 6] = s2; }
  __syncthreads();
  if (t == 0) {
    double S = aS[0] + aS[1] + aS[2] + aS[3];
    double S2 = aS2[0] + aS2[1] + aS2[2] + aS2[3];
    double mean = S / (double)(B_ * M_);
    double var = S2 / (double)(B_ * M_) - mean * mean;
    float rstd = 1.0f / sqrtf((float)var + 1e-5f);
    stats[o] = (float)mean;
    stats[C2_ + o] = gamma[o] * rstd;
  }
}

// ---------------------------------------------------------------------------
// 4) BN apply, in place on the (B,C2,M) output region. float4-vectorized.
// ---------------------------------------------------------------------------
__global__ __launch_bounds__(256) void bn_apply_kernel(float* __restrict__ outp,
                                                       const float* __restrict__ stats,
                                                       const float* __restrict__ beta) {
  const int i4 = blockIdx.x * 256 + threadIdx.x;  // B_*C2_*M_/4 = 262144
  const int ch = (i4 >> 9) & 255;                 // M_/4 = 512 float4 / chan
  const float mean = stats[ch];
  const float scale = stats[C2_ + ch];
  const float bt = beta[ch];
  float4 v = ((const float4*)outp)[i4];
  v.x = (v.x - mean) * scale + bt;
  v.y = (v.y - mean) * scale + bt;
  v.z = (v.z - mean) * scale + bt;
  v.w = (v.w - mean) * scale + bt;
  ((float4*)outp)[i4] = v;
}

// ---------------------------------------------------------------------------
extern "C" void kernel_launch(void* const* d_in, const int* in_sizes, int n_in,
                              void* d_out, int out_size, void* d_ws, size_t ws_size,
                              hipStream_t stream) {
  const float* xyz   = (const float*)d_in[0];
  const float* x     = (const float*)d_in[1];
  const float* W1    = (const float*)d_in[2];
  const float* b1    = (const float*)d_in[3];
  const float* W2    = (const float*)d_in[4];
  const float* b2    = (const float*)d_in[5];
  const float* gamma = (const float*)d_in[6];
  const float* beta  = (const float*)d_in[7];

  float* new_xyz = (float*)d_out;                       // (B, M, 3)
  float* outp    = (float*)d_out + (size_t)B_ * M_ * 3; // (B, C2, M)
  float* stats   = (float*)d_ws;                        // 2*C2 floats = 2 KB

  fps_kernel<<<B_, 1024, 0, stream>>>(xyz, new_xyz);
  mlp_kernel<<<B_ * M_, 256, 0, stream>>>(xyz, x, W1, b1, W2, b2, new_xyz, outp);
  bn_stats_kernel<<<C2_, 256, 0, stream>>>(outp, gamma, stats);
  bn_apply_kernel<<<(B_ * C2_ * M_ / 4) / 256, 256, 0, stream>>>(outp, stats, beta);
}

// Round 6
// 2779.372 us; speedup vs baseline: 1.4991x; 1.4991x over previous
//
#include <hip/hip_runtime.h>
#include <cstdint>
#include <cstddef>

#define B_   2
#define N_   8192
#define M_   2048
#define K_   32
#define C0_  64
#define C1_  128
#define C2_  256
#define CIN_ 67

// Exact-match distance: reference computes sum((a-b)**2, axis=-1) in f32 as
// ((dx^2 + dy^2) + dz^2) with no FMA contraction. _rn intrinsics forbid
// contract-fast fma fusion (would flip argmax / radius-boundary decisions).
__device__ __forceinline__ float sqdist_rn(float ax, float ay, float az,
                                           float bx, float by, float bz) {
  float dx = __fsub_rn(ax, bx);
  float dy = __fsub_rn(ay, by);
  float dz = __fsub_rn(az, bz);
  return __fadd_rn(__fadd_rn(__fmul_rn(dx, dx), __fmul_rn(dy, dy)),
                   __fmul_rn(dz, dz));
}

__device__ __forceinline__ int morton8(int ix, int iy, int iz) {
  int m = 0;
#pragma unroll
  for (int b = 0; b < 3; ++b) {
    m |= (((ix >> b) & 1) << (3 * b + 2)) | (((iy >> b) & 1) << (3 * b + 1)) |
         (((iz >> b) & 1) << (3 * b + 0));
  }
  return m;
}

// u64 max across the wave via paired DPP (row_shr 1/2/4/8, row_bcast 15/31);
// cumulative max lands in lane 63. bound_ctrl=false + old=self => lanes with
// no source contribute their own value (max(v,v)=v). Exact tie-break is baked
// into the key (d | inv_pid | pos), so a plain unsigned max is sufficient.
__device__ __forceinline__ unsigned long long wave_max_u64_dpp(unsigned long long k) {
#define FPS_STEP(ctrl)                                                         \
  {                                                                            \
    int klo = (int)(unsigned)k, khi = (int)(unsigned)(k >> 32);                \
    int olo = __builtin_amdgcn_update_dpp(klo, klo, ctrl, 0xf, 0xf, false);    \
    int ohi = __builtin_amdgcn_update_dpp(khi, khi, ctrl, 0xf, 0xf, false);    \
    unsigned long long ok =                                                    \
        ((unsigned long long)(unsigned)ohi << 32) | (unsigned)olo;             \
    if (ok > k) k = ok;                                                        \
  }
  FPS_STEP(0x111)  // row_shr:1
  FPS_STEP(0x112)  // row_shr:2
  FPS_STEP(0x114)  // row_shr:4
  FPS_STEP(0x118)  // row_shr:8
  FPS_STEP(0x142)  // row_bcast:15
  FPS_STEP(0x143)  // row_bcast:31
#undef FPS_STEP
  return k;
}

// ---------------------------------------------------------------------------
// 1) Furthest point sampling: exact spatial pruning, packed-u64-key argmax,
//    round-4 two-barrier shape (dirty waves update -> barrier -> WAVE0 ONLY
//    reduces 16 slots -> barrier). One block (1024 thr, 16 waves) per batch.
//    Key = (d_bits<<26) | (8191-pid)<<13 | pos : u64 max == (max d, then min
//    ORIGINAL index) == jnp.argmax first-occurrence; pos payload gives the
//    winner's slot in spt for a single b128 coord fetch.
//    Per-thread cached: tkey (bucket argmax key), thrT (skip threshold,
//    recomputed with sqrt only when bd changes). Per-wave cached: slot sKey[w]
//    (clean waves don't rewrite; single-buffered slots are safe: barrier A
//    fences writes->reads, barrier B fences reads->next writes).
//    Counting-sort scatter order is atomic-nondeterministic but output-
//    invariant: updates are exact min ops, skips provably no-op, ties break
//    on original pid inside the key.
// ---------------------------------------------------------------------------
__global__ __launch_bounds__(1024, 1) void fps_kernel(const float* __restrict__ xyz,
                                                      float* __restrict__ new_xyz) {
  const int b = blockIdx.x;
  const int t = threadIdx.x;
  const int lane = t & 63;
  const int w = t >> 6;
  const float* xb = xyz + (size_t)b * N_ * 3;

  __shared__ float4 spt[N_];                   // 128 KiB sorted {x,y,z,pid}
  __shared__ float snew3[M_ * 3];              // 24 KiB winner ring
  __shared__ unsigned long long sKey[16];      // per-wave candidate slots
  __shared__ int hist[512];
  __shared__ int boff[512];
  __shared__ int wsum[8];

  // ---- counting sort by morton cell ----
  if (t < 512) hist[t] = 0;
  __syncthreads();
#pragma unroll
  for (int rr = 0; rr < 8; ++rr) {
    int i = rr * 1024 + t;
    float X = xb[i * 3 + 0], Y = xb[i * 3 + 1], Z = xb[i * 3 + 2];
    int ix = min(7, max(0, (int)(X * 8.0f)));
    int iy = min(7, max(0, (int)(Y * 8.0f)));
    int iz = min(7, max(0, (int)(Z * 8.0f)));
    atomicAdd(&hist[morton8(ix, iy, iz)], 1);
  }
  __syncthreads();
  // exclusive scan of 512 bins (8 active waves)
  {
    int ov = (t < 512) ? hist[t] : 0;
    int v = ov;
#pragma unroll
    for (int off = 1; off < 64; off <<= 1) {
      int n = __shfl_up(v, off);
      if (lane >= off) v += n;
    }
    if (t < 512 && lane == 63) wsum[w] = v;
    __syncthreads();
    if (t == 0) {
      int acc = 0;
#pragma unroll
      for (int j = 0; j < 8; ++j) { int x0 = wsum[j]; wsum[j] = acc; acc += x0; }
    }
    __syncthreads();
    if (t < 512) boff[t] = v - ov + wsum[w];
  }
  __syncthreads();
#pragma unroll
  for (int rr = 0; rr < 8; ++rr) {
    int i = rr * 1024 + t;
    float X = xb[i * 3 + 0], Y = xb[i * 3 + 1], Z = xb[i * 3 + 2];
    int ix = min(7, max(0, (int)(X * 8.0f)));
    int iy = min(7, max(0, (int)(Y * 8.0f)));
    int iz = min(7, max(0, (int)(Z * 8.0f)));
    int pos = atomicAdd(&boff[morton8(ix, iy, iz)], 1);
    float4 v4; v4.x = X; v4.y = Y; v4.z = Z; v4.w = __int_as_float(i);
    spt[pos] = v4;
  }
  if (t == 0) {
    snew3[0] = xb[0]; snew3[1] = xb[1]; snew3[2] = xb[2];  // first index = 0
  }
  __syncthreads();

  // ---- per-thread bucket: 8 points + precomputed key low bits ----
  float px[8], py[8], pz[8], d[8];
  unsigned lowk[8];
#pragma unroll
  for (int k = 0; k < 8; ++k) {
    float4 v4 = spt[8 * t + k];
    px[k] = v4.x; py[k] = v4.y; pz[k] = v4.z;
    int pid = __float_as_int(v4.w);
    lowk[k] = ((unsigned)(8191 - pid) << 13) | (unsigned)(8 * t + k);
    d[k] = 1e10f;  // == f32(10000000000.0), matches jnp init exactly
  }
  float cx = 0.f, cy = 0.f, cz = 0.f;
#pragma unroll
  for (int k = 0; k < 8; ++k) { cx += px[k]; cy += py[k]; cz += pz[k]; }
  cx *= 0.125f; cy *= 0.125f; cz *= 0.125f;
  float r2m = 0.f;
#pragma unroll
  for (int k = 0; k < 8; ++k) {
    float dx = px[k] - cx, dy = py[k] - cy, dz = pz[k] - cz;
    r2m = fmaxf(r2m, dx * dx + dy * dy + dz * dz);
  }
  const float rad = sqrtf(r2m) * 1.00002f + 1e-12f;

  unsigned long long tkey = 0ull;  // per-thread cached bucket-argmax key
  float thrT = 3e38f;              // never skip until first update sets it

  for (int it = 1; it < M_; ++it) {
    const float lx = snew3[it * 3 - 3];
    const float ly = snew3[it * 3 - 2];
    const float lz = snew3[it * 3 - 1];

    // ---- conservative skip test, sqrt-free on the clean path ----
    float ex = lx - cx, ey = ly - cy, ez = lz - cz;
    float dc2 = ex * ex + ey * ey + ez * ez;
    bool dirtyLane = dc2 <= thrT;
    if (__ballot(dirtyLane) != 0ull) {  // wave-uniform: wave must refresh
      if (dirtyLane) {
        unsigned long long nk = 0ull;
#pragma unroll
        for (int k = 0; k < 8; ++k) {
          float dist = sqdist_rn(px[k], py[k], pz[k], lx, ly, lz);
          float dm = fminf(d[k], dist);
          d[k] = dm;
          unsigned long long key =
              ((unsigned long long)(unsigned)__float_as_int(dm) << 26) | lowk[k];
          nk = (key > nk) ? key : nk;
        }
        tkey = nk;
        float bd = __int_as_float((int)(unsigned)(tkey >> 26));
        float sr = sqrtf(bd * 1.0001f) + rad;  // conservative: margins dwarf ulp
        thrT = sr * sr;
      }
      unsigned long long wk = wave_max_u64_dpp(tkey);
      if (lane == 63) sKey[w] = wk;
    }
    __syncthreads();  // A: slot writes -> wave0 reads
    if (w == 0) {
      unsigned long long key = sKey[lane & 15];
#define FPS_STEP2(ctrl)                                                        \
      {                                                                        \
        int klo = (int)(unsigned)key, khi = (int)(unsigned)(key >> 32);        \
        int olo = __builtin_amdgcn_update_dpp(klo, klo, ctrl, 0xf, 0xf, false);\
        int ohi = __builtin_amdgcn_update_dpp(khi, khi, ctrl, 0xf, 0xf, false);\
        unsigned long long okey =                                              \
            ((unsigned long long)(unsigned)ohi << 32) | (unsigned)olo;         \
        if (okey > key) key = okey;                                            \
      }
      FPS_STEP2(0x111)  // row_shr:1
      FPS_STEP2(0x112)  // row_shr:2
      FPS_STEP2(0x114)  // row_shr:4
      FPS_STEP2(0x118)  // row_shr:8
#undef FPS_STEP2
      int winPos = __builtin_amdgcn_readlane((int)(unsigned)key, 15) & 8191;
      float4 c = spt[winPos];  // wave-uniform addr -> broadcast b128
      if (lane == 0) {
        snew3[it * 3 + 0] = c.x;
        snew3[it * 3 + 1] = c.y;
        snew3[it * 3 + 2] = c.z;
      }
    }
    __syncthreads();  // B: snew3[it] visible; slots stable for next writes
  }

  // ---- coalesced dump of selected coords ----
  for (int i = t; i < M_ * 3; i += 1024) {
    new_xyz[(size_t)b * M_ * 3 + i] = snew3[i];
  }
}

// ---------------------------------------------------------------------------
// 2) Fused ball-query + grouping + MLP(67->128 relu ->256) + max over K.
//    One block (256 thr) per centroid. Ball query: wave w scans index chunk
//    [w*2048,(w+1)*2048) in order, ballot-appends first <=32 valid to its own
//    LDS list; lists concat in wave order == global index order (pointnet2
//    first-K semantics). Writes pre-BN pooled features TRANSPOSED into the
//    final (B,C2,M) output region (no scratch needed).
// ---------------------------------------------------------------------------
__global__ __launch_bounds__(256) void mlp_kernel(const float* __restrict__ xyz,
                                                  const float* __restrict__ x,
                                                  const float* __restrict__ W1,
                                                  const float* __restrict__ b1,
                                                  const float* __restrict__ W2,
                                                  const float* __restrict__ b2,
                                                  const float* __restrict__ new_xyz,
                                                  float* __restrict__ outp) {
  __shared__ float sGRed[32 * 69];   // group tile; unioned w/ 8x256 max-red
  __shared__ float sU[128 * 69];     // W1 staged; unioned w/ 32x256 W2 tile
  __shared__ float sH1[32 * 132];
  __shared__ int sWIdx[4][K_];
  __shared__ int sWCnt[4];
  __shared__ int sIdx[K_];
  __shared__ float sQ[3];

  const int gm = blockIdx.x;
  const int b = gm >> 11;    // M_ = 2048
  const int m = gm & 2047;
  const int t = threadIdx.x;
  const int lane = t & 63;
  const int w = t >> 6;
  const float* xb = xyz + (size_t)b * N_ * 3;

  if (t < 3) sQ[t] = new_xyz[(size_t)gm * 3 + t];
  __syncthreads();
  const float qx = sQ[0], qy = sQ[1], qz = sQ[2];
  // (float)(0.1*0.1) = 0x3C23D70A; 0.1f*0.1f rounds differently — wrong.
  const float R2 = (float)(0.1 * 0.1);

  // ---- ball query ----
  {
    int cnt = 0;
    const int cbeg = w * 2048, cend = cbeg + 2048;
    for (int base = cbeg; base < cend; base += 64) {
      int p = base + lane;
      float d2 = sqdist_rn(qx, qy, qz, xb[p * 3 + 0], xb[p * 3 + 1], xb[p * 3 + 2]);
      bool valid = d2 < R2;
      unsigned long long mask = __ballot(valid);
      if (valid) {
        int pos = cnt + __popcll(mask & ((1ull << lane) - 1ull));
        if (pos < K_) sWIdx[w][pos] = p;
      }
      cnt += __popcll(mask);
      if (cnt >= K_) break;  // wave-uniform
    }
    if (lane == 0) sWCnt[w] = (cnt < K_) ? cnt : K_;
  }
  __syncthreads();
  if (t < K_) {
    int c0 = sWCnt[0], c1 = sWCnt[1], c2 = sWCnt[2], c3 = sWCnt[3];
    int s1 = c0 + c1, s2 = s1 + c2, s3 = s2 + c3;
    int j = t, idx;
    if (j < c0) idx = sWIdx[0][j];
    else if (j < s1) idx = sWIdx[1][j - c0];
    else if (j < s2) idx = sWIdx[2][j - s1];
    else if (j < s3) idx = sWIdx[3][j - s2];
    else {
      int fw = c0 ? 0 : (c1 ? 1 : (c2 ? 2 : 3));
      idx = (s3 > 0) ? sWIdx[fw][0] : 0;  // fill with first valid index
    }
    sIdx[j] = idx;
  }
  __syncthreads();

  // ---- grouping: rel coords + features into sGRed (32 x 69 padded) ----
  if (t < K_) {
    int id = sIdx[t];
    sGRed[t * 69 + 0] = xb[id * 3 + 0] - qx;
    sGRed[t * 69 + 1] = xb[id * 3 + 1] - qy;
    sGRed[t * 69 + 2] = xb[id * 3 + 2] - qz;
  }
  {
    int r = t & 31;
    int c0 = (t >> 5) * 8;
    int id = sIdx[r];
    const float* xf = x + ((size_t)b * C0_ + c0) * N_ + id;
#pragma unroll
    for (int j = 0; j < 8; ++j) sGRed[r * 69 + 3 + c0 + j] = xf[(size_t)j * N_];
  }
  for (int i = t; i < C1_ * CIN_; i += 256) {
    sU[(i / CIN_) * 69 + (i % CIN_)] = W1[i];
  }
  __syncthreads();

  const int ol = t & 31;  // output-lane: o = ol + 32*j
  const int rg = t >> 5;  // row group: rows rg*4 .. rg*4+3

  // ---- layer 1: h1 = relu(G @ W1^T + b1), 4 rows x 4 outs per thread ----
  float acc[4][4] = {{0.f}};
  for (int c = 0; c < CIN_; ++c) {
    float g[4], wv[4];
#pragma unroll
    for (int i = 0; i < 4; ++i) g[i] = sGRed[(rg * 4 + i) * 69 + c];
#pragma unroll
    for (int j = 0; j < 4; ++j) wv[j] = sU[(ol + 32 * j) * 69 + c];
#pragma unroll
    for (int i = 0; i < 4; ++i)
#pragma unroll
      for (int j = 0; j < 4; ++j) acc[i][j] += g[i] * wv[j];
  }
#pragma unroll
  for (int j = 0; j < 4; ++j) {
    float bias = b1[ol + 32 * j];
#pragma unroll
    for (int i = 0; i < 4; ++i) {
      float v = acc[i][j] + bias;
      sH1[(rg * 4 + i) * 132 + ol + 32 * j] = fmaxf(v, 0.0f);
    }
  }

  // ---- layer 2: h2 = h1 @ W2^T, 4 rows x 8 outs per thread ----
  float acc2[4][8] = {{0.f}};
  for (int ct = 0; ct < 4; ++ct) {
    __syncthreads();  // sU reuse safe; (ct==0) also covers sH1 writes
    const float4* w4 = (const float4*)(W2 + (size_t)t * C1_ + ct * 32);
#pragma unroll
    for (int jj = 0; jj < 8; ++jj) {
      float4 v = w4[jj];
      sU[(jj * 4 + 0) * 256 + t] = v.x;
      sU[(jj * 4 + 1) * 256 + t] = v.y;
      sU[(jj * 4 + 2) * 256 + t] = v.z;
      sU[(jj * 4 + 3) * 256 + t] = v.w;
    }
    __syncthreads();
    for (int cc = 0; cc < 32; ++cc) {
      float h[4], wv[8];
#pragma unroll
      for (int i = 0; i < 4; ++i) h[i] = sH1[(rg * 4 + i) * 132 + ct * 32 + cc];
#pragma unroll
      for (int j = 0; j < 8; ++j) wv[j] = sU[cc * 256 + ol + 32 * j];
#pragma unroll
      for (int i = 0; i < 4; ++i)
#pragma unroll
        for (int j = 0; j < 8; ++j) acc2[i][j] += h[i] * wv[j];
    }
  }

  // ---- max over K, + b2 (max(x)+c == max(x+c): RN is monotone) ----
  __syncthreads();  // group tile dead; reuse sGRed as reduction buffer
#pragma unroll
  for (int j = 0; j < 8; ++j) {
    float pm = acc2[0][j];
#pragma unroll
    for (int i = 1; i < 4; ++i) pm = fmaxf(pm, acc2[i][j]);
    sGRed[rg * 256 + ol + 32 * j] = pm;
  }
  __syncthreads();
  {
    int o = t;
    float v = sGRed[o];
#pragma unroll
    for (int g = 1; g < 8; ++g) v = fmaxf(v, sGRed[g * 256 + o]);
    v += b2[o];
    // transposed store into final (B, C2, M) layout (pre-BN)
    outp[((size_t)(b * C2_ + o)) * M_ + m] = v;
  }
}

// ---------------------------------------------------------------------------
// 3) BN stats per channel (deterministic, double accum). One block / channel.
// ---------------------------------------------------------------------------
__global__ __launch_bounds__(256) void bn_stats_kernel(const float* __restrict__ outp,
                                                       const float* __restrict__ gamma,
                                                       float* __restrict__ stats) {
  const int o = blockIdx.x;
  const int t = threadIdx.x;
  double s = 0.0, s2 = 0.0;
  for (int b = 0; b < B_; ++b) {
    const float* p = outp + ((size_t)(b * C2_ + o)) * M_;
    for (int i = t; i < M_; i += 256) {
      float v = p[i];
      s += (double)v;
      s2 += (double)v * (double)v;
    }
  }
#pragma unroll
  for (int off = 32; off > 0; off >>= 1) {
    s += __shfl_xor(s, off);
    s2 += __shfl_xor(s2, off);
  }
  __shared__ double aS[4], aS2[4];
  if ((t & 63) == 0) { aS[t >> 6] = s; aS2[t >> 6] = s2; }
  __syncthreads();
  if (t == 0) {
    double S = aS[0] + aS[1] + aS[2] + aS[3];
    double S2 = aS2[0] + aS2[1] + aS2[2] + aS2[3];
    double mean = S / (double)(B_ * M_);
    double var = S2 / (double)(B_ * M_) - mean * mean;
    float rstd = 1.0f / sqrtf((float)var + 1e-5f);
    stats[o] = (float)mean;
    stats[C2_ + o] = gamma[o] * rstd;
  }
}

// ---------------------------------------------------------------------------
// 4) BN apply, in place on the (B,C2,M) output region. float4-vectorized.
// ---------------------------------------------------------------------------
__global__ __launch_bounds__(256) void bn_apply_kernel(float* __restrict__ outp,
                                                       const float* __restrict__ stats,
                                                       const float* __restrict__ beta) {
  const int i4 = blockIdx.x * 256 + threadIdx.x;  // B_*C2_*M_/4 = 262144
  const int ch = (i4 >> 9) & 255;                 // M_/4 = 512 float4 / chan
  const float mean = stats[ch];
  const float scale = stats[C2_ + ch];
  const float bt = beta[ch];
  float4 v = ((const float4*)outp)[i4];
  v.x = (v.x - mean) * scale + bt;
  v.y = (v.y - mean) * scale + bt;
  v.z = (v.z - mean) * scale + bt;
  v.w = (v.w - mean) * scale + bt;
  ((float4*)outp)[i4] = v;
}

// ---------------------------------------------------------------------------
extern "C" void kernel_launch(void* const* d_in, const int* in_sizes, int n_in,
                              void* d_out, int out_size, void* d_ws, size_t ws_size,
                              hipStream_t stream) {
  const float* xyz   = (const float*)d_in[0];
  const float* x     = (const float*)d_in[1];
  const float* W1    = (const float*)d_in[2];
  const float* b1    = (const float*)d_in[3];
  const float* W2    = (const float*)d_in[4];
  const float* b2    = (const float*)d_in[5];
  const float* gamma = (const float*)d_in[6];
  const float* beta  = (const float*)d_in[7];

  float* new_xyz = (float*)d_out;                       // (B, M, 3)
  float* outp    = (float*)d_out + (size_t)B_ * M_ * 3; // (B, C2, M)
  float* stats   = (float*)d_ws;                        // 2*C2 floats = 2 KB

  fps_kernel<<<B_, 1024, 0, stream>>>(xyz, new_xyz);
  mlp_kernel<<<B_ * M_, 256, 0, stream>>>(xyz, x, W1, b1, W2, b2, new_xyz, outp);
  bn_stats_kernel<<<C2_, 256, 0, stream>>>(outp, gamma, stats);
  bn_apply_kernel<<<(B_ * C2_ * M_ / 4) / 256, 256, 0, stream>>>(outp, stats, beta);
}